// Round 3
// baseline (145.006 us; speedup 1.0000x reference)
//
#include <hip/hip_runtime.h>
#include <hip/hip_bf16.h>

#define NTOT   8192
#define BHALF  4096
#define DDIM   256
#define NPART  4      // partial copies of s_part to spread atomic contention
#define EXPSCALE 14.4269504088896341f   // 10 / ln(2): exp(10x) = exp2(EXPSCALE*x)

typedef __attribute__((ext_vector_type(8))) short bf16x8_t;  // 8 bf16 = 4 VGPRs
typedef __attribute__((ext_vector_type(4))) float f32x4_t;   // MFMA C/D

__device__ inline unsigned short f2bf(float x) {
    __hip_bfloat16 h = __float2bfloat16(x);
    return __builtin_bit_cast(unsigned short, h);
}

// ---- kernel 1: normalize pair k (rows k, k+B) -> bf16 zn; posdot; zero s_part ----
__global__ void norm_pair_kernel(const float* __restrict__ zi,
                                 const float* __restrict__ zj,
                                 unsigned short* __restrict__ zn,
                                 float* __restrict__ posdot,
                                 float* __restrict__ s_part) {
    int gtid = blockIdx.x * 256 + threadIdx.x;
    if (gtid < NTOT * NPART) s_part[gtid] = 0.0f;   // done before gemm (stream order)
    int k    = gtid >> 6;
    int lane = gtid & 63;
    float4 vi = reinterpret_cast<const float4*>(zi + (size_t)k * DDIM)[lane];
    float4 vj = reinterpret_cast<const float4*>(zj + (size_t)k * DDIM)[lane];
    float ssi = vi.x*vi.x + vi.y*vi.y + vi.z*vi.z + vi.w*vi.w;
    float ssj = vj.x*vj.x + vj.y*vj.y + vj.z*vj.z + vj.w*vj.w;
    float dot = vi.x*vj.x + vi.y*vj.y + vi.z*vj.z + vi.w*vj.w;
    #pragma unroll
    for (int off = 32; off >= 1; off >>= 1) {
        ssi += __shfl_xor(ssi, off);
        ssj += __shfl_xor(ssj, off);
        dot += __shfl_xor(dot, off);
    }
    float ri = 1.0f / fmaxf(sqrtf(ssi), 1e-8f);
    float rj = 1.0f / fmaxf(sqrtf(ssj), 1e-8f);
    ushort4 oi, oj;
    oi.x = f2bf(vi.x * ri); oi.y = f2bf(vi.y * ri);
    oi.z = f2bf(vi.z * ri); oi.w = f2bf(vi.w * ri);
    oj.x = f2bf(vj.x * rj); oj.y = f2bf(vj.y * rj);
    oj.z = f2bf(vj.z * rj); oj.w = f2bf(vj.w * rj);
    reinterpret_cast<ushort4*>(zn + (size_t)k * DDIM)[lane] = oi;
    reinterpret_cast<ushort4*>(zn + (size_t)(k + BHALF) * DDIM)[lane] = oj;
    if (lane == 0) posdot[k] = dot * ri * rj * 10.0f;
}

// ---- kernel 2: symmetric fused GEMM + exp-sum, v4: barrier-free per-wave ----
// v1-v3 post-mortem: ~45-48 us invariant under occupancy (17->31%) and prefetch
// changes; MfmaUtil pinned at 13%. Diagnosis: block-wide barrier convoy -- per
// strip, 256 ds_read_b128 burst into the single LDS pipe, then MFMA, then VALU
// epilogue, phases summing not overlapping; co-resident blocks phase-correlated.
// v4 deletes the convoy: NO LDS, NO barriers. Each wave owns 32 rows (A-frags
// resident in 64 VGPRs), streams 64-col B strips directly from L2 into register
// fragments. Upper-triangle tiling (32 rows x 64 cols); tile (R,C) computed iff
// C >= R>>1; diag tile (C == R>>1) contributes only cells gc > gr; every upper
// cell adds to rowsum[gr] AND (mirror) colsum[gc]. Row-pair (p, 255-p) gives
// each of 16 residue-waves 8-9 strips total (b1+b2=127 balance). 2048 waves =
// 8/CU, all resident; waves drift freely so L2 loads, MFMA, exp2 overlap
// statistically across waves instead of phase-aligning.
__global__ void __launch_bounds__(256, 2)
gemm_sym_kernel(const unsigned short* __restrict__ zn,
                float* __restrict__ s_part) {
    const int tid  = threadIdx.x;
    const int lane = tid & 63;
    const int wv   = tid >> 6;
    const int m    = lane & 15;
    const int quad = lane >> 4;
    const int wid  = blockIdx.x * 4 + wv;   // 0..2047
    const int p    = wid >> 4;              // pair index 0..127
    const int j    = wid & 15;              // residue lane 0..15

    // spread atomic contention: rows hit by 16 j-waves -> copy j&3;
    // cols hit by many pairs -> copy p&3.
    float* rowPart = s_part + (size_t)(j & (NPART - 1)) * NTOT;
    float* colPart = s_part + (size_t)(p & (NPART - 1)) * NTOT;

    #pragma unroll
    for (int phase = 0; phase < 2; ++phase) {
        const int R  = phase ? (255 - p) : p;   // row-tile 0..255 (32 rows)
        const int b  = R >> 1;                  // first col-strip touching diag
        const int jj = phase ? (15 - j) : j;    // anti-correlated residue
        int C = b + ((jj - b) & 15);            // first strip ≡ jj (mod 16), >= b
        if (C >= 128) continue;                 // this wave has no strips here

        // A fragments: rows R*32 + rf*16 + m, k-chunk kk*32 + quad*8 (+0..7)
        bf16x8_t afrag[2][8];
        #pragma unroll
        for (int rf = 0; rf < 2; ++rf) {
            const unsigned short* arow =
                zn + (size_t)((R << 5) + rf*16 + m) * DDIM + quad*8;
            #pragma unroll
            for (int kk = 0; kk < 8; ++kk)
                afrag[rf][kk] = *reinterpret_cast<const bf16x8_t*>(arow + kk*32);
        }

        float rowacc[2][4] = {{0.f,0.f,0.f,0.f},{0.f,0.f,0.f,0.f}};

        for (; C < 128; C += 16) {
            const bool diag = (C == b);
            const int C0 = C << 6;

            f32x4_t acc[2][4];
            #pragma unroll
            for (int rf = 0; rf < 2; ++rf)
                #pragma unroll
                for (int cf = 0; cf < 4; ++cf)
                    acc[rf][cf] = (f32x4_t){0.f,0.f,0.f,0.f};

            // B fragments straight from global (L2-resident): per cf, 8 x b128
            // at one base + imm offsets; MFMAs consume as they land (compiler
            // pipelines across the unrolled cf groups).
            #pragma unroll
            for (int cf = 0; cf < 4; ++cf) {
                const unsigned short* brow =
                    zn + (size_t)(C0 + cf*16 + m) * DDIM + quad*8;
                bf16x8_t bfr[8];
                #pragma unroll
                for (int kk = 0; kk < 8; ++kk)
                    bfr[kk] = *reinterpret_cast<const bf16x8_t*>(brow + kk*32);
                #pragma unroll
                for (int kk = 0; kk < 8; ++kk) {
                    acc[0][cf] = __builtin_amdgcn_mfma_f32_16x16x32_bf16(
                                     afrag[0][kk], bfr[kk], acc[0][cf], 0, 0, 0);
                    acc[1][cf] = __builtin_amdgcn_mfma_f32_16x16x32_bf16(
                                     afrag[1][kk], bfr[kk], acc[1][cf], 0, 0, 0);
                }
            }

            // fused epilogue: e = exp(10*sim); on the diag tile keep only the
            // strictly-upper wedge (gc > gr) -- its mirror is covered via colsum
            // by other diag tiles; off-diag tiles are entirely upper.
            float colsum[4] = {0.f, 0.f, 0.f, 0.f};
            #pragma unroll
            for (int cf = 0; cf < 4; ++cf) {
                const int gc = C0 + cf*16 + m;
                #pragma unroll
                for (int rf = 0; rf < 2; ++rf)
                    #pragma unroll
                    for (int r = 0; r < 4; ++r) {
                        float e = exp2f(acc[rf][cf][r] * EXPSCALE);
                        if (diag) {
                            int gr = (R << 5) + rf*16 + quad*4 + r;
                            e = (gc > gr) ? e : 0.f;
                        }
                        rowacc[rf][r] += e;
                        colsum[cf]    += e;
                    }
            }
            // reduce colsum over the wave's 32 rows (quad groups), then each
            // lane flushes one column: lane = quad*16+m -> col C0+lane.
            #pragma unroll
            for (int cf = 0; cf < 4; ++cf) {
                colsum[cf] += __shfl_xor(colsum[cf], 16);
                colsum[cf] += __shfl_xor(colsum[cf], 32);
            }
            float v = colsum[0];
            v = (quad == 1) ? colsum[1] : v;
            v = (quad == 2) ? colsum[2] : v;
            v = (quad == 3) ? colsum[3] : v;
            atomicAdd(&colPart[C0 + lane], v);
        }

        // row totals: reduce over 16 m-lanes, one atomic per row per phase
        #pragma unroll
        for (int rf = 0; rf < 2; ++rf)
            #pragma unroll
            for (int r = 0; r < 4; ++r) {
                float v = rowacc[rf][r];
                v += __shfl_xor(v, 1);
                v += __shfl_xor(v, 2);
                v += __shfl_xor(v, 4);
                v += __shfl_xor(v, 8);
                if (m == 0)
                    atomicAdd(&rowPart[(R << 5) + rf*16 + quad*4 + r], v);
            }
    }
}

// ---- kernel 3: loss_k = log(sum_p s_part[p][k]) - posdot[k%B]; masked mean ----
__global__ void finalize_kernel(const float* __restrict__ s_part,
                                const float* __restrict__ posdot,
                                const unsigned char* __restrict__ mask,
                                float* __restrict__ out) {
    int tid = threadIdx.x, lane = tid & 63, wv = tid >> 6;
    float tot = 0.f, cnt = 0.f;
    #pragma unroll
    for (int si = 0; si < NTOT / 1024; ++si) {
        int k = si * 1024 + tid;
        int kb = k & (BHALF - 1);
        if (mask[kb] != 0) {
            float sk = s_part[k] + s_part[NTOT + k]
                     + s_part[2*NTOT + k] + s_part[3*NTOT + k];
            tot += __logf(sk) - posdot[kb];
            cnt += 1.f;
        }
    }
    #pragma unroll
    for (int off = 32; off >= 1; off >>= 1) {
        tot += __shfl_xor(tot, off);
        cnt += __shfl_xor(cnt, off);
    }
    __shared__ float st[16], sc[16];
    if (lane == 0) { st[wv] = tot; sc[wv] = cnt; }
    __syncthreads();
    if (tid == 0) {
        float T = 0.f, C = 0.f;
        #pragma unroll
        for (int i = 0; i < 16; ++i) { T += st[i]; C += sc[i]; }
        out[0] = (C > 0.f) ? (T / fmaxf(C, 1.f)) : 0.f;
    }
}

extern "C" void kernel_launch(void* const* d_in, const int* in_sizes, int n_in,
                              void* d_out, int out_size, void* d_ws, size_t ws_size,
                              hipStream_t stream) {
    const float* zi = (const float*)d_in[0];
    const float* zj = (const float*)d_in[1];
    const unsigned char* mask = (const unsigned char*)d_in[2];
    float* out = (float*)d_out;

    // ws: [0,4MB) zn bf16; s_part[NPART][8192] f32; posdot[4096] f32
    unsigned short* zn = (unsigned short*)d_ws;
    float* s_part = (float*)((char*)d_ws + (size_t)NTOT * DDIM * 2);
    float* posdot = s_part + NPART * NTOT;

    norm_pair_kernel<<<dim3(1024), dim3(256), 0, stream>>>(zi, zj, zn, posdot, s_part);
    gemm_sym_kernel<<<dim3(512), dim3(256), 0, stream>>>(zn, s_part);
    finalize_kernel<<<dim3(1), dim3(1024), 0, stream>>>(s_part, posdot, mask, out);
}

// Round 4
// 139.192 us; speedup vs baseline: 1.0418x; 1.0418x over previous
//
#include <hip/hip_runtime.h>
#include <hip/hip_bf16.h>

#define NTOT   8192
#define BHALF  4096
#define DDIM   256
#define NPART  4      // partial copies of s_part to spread atomic contention
#define EXPSCALE 14.4269504088896341f   // 10 / ln(2): exp(10x) = exp2(EXPSCALE*x)

typedef __attribute__((ext_vector_type(8))) short bf16x8_t;  // 8 bf16 = 4 VGPRs
typedef __attribute__((ext_vector_type(4))) float f32x4_t;   // MFMA C/D

__device__ inline unsigned short f2bf(float x) {
    __hip_bfloat16 h = __float2bfloat16(x);
    return __builtin_bit_cast(unsigned short, h);
}

// ---- kernel 1: normalize pair k (rows k, k+B) -> bf16 zn; posdot; zero s_part ----
__global__ void norm_pair_kernel(const float* __restrict__ zi,
                                 const float* __restrict__ zj,
                                 unsigned short* __restrict__ zn,
                                 float* __restrict__ posdot,
                                 float* __restrict__ s_part) {
    int gtid = blockIdx.x * 256 + threadIdx.x;
    if (gtid < NTOT * NPART) s_part[gtid] = 0.0f;   // done before gemm (stream order)
    int k    = gtid >> 6;
    int lane = gtid & 63;
    float4 vi = reinterpret_cast<const float4*>(zi + (size_t)k * DDIM)[lane];
    float4 vj = reinterpret_cast<const float4*>(zj + (size_t)k * DDIM)[lane];
    float ssi = vi.x*vi.x + vi.y*vi.y + vi.z*vi.z + vi.w*vi.w;
    float ssj = vj.x*vj.x + vj.y*vj.y + vj.z*vj.z + vj.w*vj.w;
    float dot = vi.x*vj.x + vi.y*vj.y + vi.z*vj.z + vi.w*vj.w;
    #pragma unroll
    for (int off = 32; off >= 1; off >>= 1) {
        ssi += __shfl_xor(ssi, off);
        ssj += __shfl_xor(ssj, off);
        dot += __shfl_xor(dot, off);
    }
    float ri = 1.0f / fmaxf(sqrtf(ssi), 1e-8f);
    float rj = 1.0f / fmaxf(sqrtf(ssj), 1e-8f);
    ushort4 oi, oj;
    oi.x = f2bf(vi.x * ri); oi.y = f2bf(vi.y * ri);
    oi.z = f2bf(vi.z * ri); oi.w = f2bf(vi.w * ri);
    oj.x = f2bf(vj.x * rj); oj.y = f2bf(vj.y * rj);
    oj.z = f2bf(vj.z * rj); oj.w = f2bf(vj.w * rj);
    reinterpret_cast<ushort4*>(zn + (size_t)k * DDIM)[lane] = oi;
    reinterpret_cast<ushort4*>(zn + (size_t)(k + BHALF) * DDIM)[lane] = oj;
    if (lane == 0) posdot[k] = dot * ri * rj * 10.0f;
}

// ---- kernel 2: symmetric fused GEMM + exp-sum, v5 ----
// v4 post-mortem: VGPR_Count=88 -> compiler REMATERIALIZED afrag from global
// inside the strip loop (zn is const) and couldn't pipeline loads -> 80 us
// latency-bound. v5 keeps v4's validated barrier-free upper-triangle math
// (absmax was 0.0) and fixes allocation: (a) amdgpu_waves_per_eu(2,2) pins the
// allocator at 2 waves/EU = 256-VGPR budget; (b) afrag values pass through an
// opaque asm so they CANNOT be rematerialized from memory; (c) 16-col strips
// with a static 2-buffer rotation (b0/b1) -> next strip's 8 global_load_dwordx4
// issue before current strip's 16 MFMAs (depth-1 per-wave prefetch, no
// barriers, no LDS); (d) 4 independent MFMA chains shorten the dep wall.
__global__ void __attribute__((amdgpu_flat_work_group_size(256, 256),
                               amdgpu_waves_per_eu(2, 2)))
gemm_sym_kernel(const unsigned short* __restrict__ zn,
                float* __restrict__ s_part) {
    const int tid  = threadIdx.x;
    const int lane = tid & 63;
    const int wv   = tid >> 6;
    const int m    = lane & 15;
    const int quad = lane >> 4;
    const int wid  = blockIdx.x * 4 + wv;   // 0..2047
    const int p    = wid >> 4;              // pair index 0..127
    const int j    = wid & 15;              // residue lane 0..15

    float* rowPart = s_part + (size_t)(j & (NPART - 1)) * NTOT;
    float* colPart = s_part + (size_t)(p & (NPART - 1)) * NTOT;

// load B fragments for 16-col strip Cs: cols Cs*16+m, k = kk*32+quad*8 (+0..7)
#define LOADB(dst, Cs) {                                                      \
    const unsigned short* bp_ = zn + (size_t)(Cs) * (16 * DDIM)               \
                                + (size_t)m * DDIM + quad * 8;                \
    _Pragma("unroll")                                                         \
    for (int kk_ = 0; kk_ < 8; ++kk_)                                         \
        dst[kk_] = *reinterpret_cast<const bf16x8_t*>(bp_ + kk_ * 32); }

// 16 MFMAs (4 independent chains) + fused exp/rowsum/colsum epilogue
#define COMPUTE(buf, Cs) {                                                    \
    const bool diag_ = (((Cs) >> 1) == R);                                    \
    f32x4_t az00 = (f32x4_t){0.f,0.f,0.f,0.f};                                \
    f32x4_t az01 = (f32x4_t){0.f,0.f,0.f,0.f};                                \
    f32x4_t az10 = (f32x4_t){0.f,0.f,0.f,0.f};                                \
    f32x4_t az11 = (f32x4_t){0.f,0.f,0.f,0.f};                                \
    _Pragma("unroll")                                                         \
    for (int kk_ = 0; kk_ < 4; ++kk_) {                                       \
        az00 = __builtin_amdgcn_mfma_f32_16x16x32_bf16(afrag[0][kk_],     buf[kk_],     az00, 0, 0, 0); \
        az10 = __builtin_amdgcn_mfma_f32_16x16x32_bf16(afrag[1][kk_],     buf[kk_],     az10, 0, 0, 0); \
        az01 = __builtin_amdgcn_mfma_f32_16x16x32_bf16(afrag[0][kk_ + 4], buf[kk_ + 4], az01, 0, 0, 0); \
        az11 = __builtin_amdgcn_mfma_f32_16x16x32_bf16(afrag[1][kk_ + 4], buf[kk_ + 4], az11, 0, 0, 0); \
    }                                                                         \
    const int gc_ = (Cs) * 16 + m;                                            \
    float colsum_ = 0.f;                                                      \
    _Pragma("unroll")                                                         \
    for (int r_ = 0; r_ < 4; ++r_) {                                          \
        float e0_ = exp2f((az00[r_] + az01[r_]) * EXPSCALE);                  \
        float e1_ = exp2f((az10[r_] + az11[r_]) * EXPSCALE);                  \
        if (diag_) {                                                          \
            int gr_ = (R << 5) + quad * 4 + r_;                               \
            e0_ = (gc_ > gr_)      ? e0_ : 0.f;                               \
            e1_ = (gc_ > gr_ + 16) ? e1_ : 0.f;                               \
        }                                                                     \
        rowacc[0][r_] += e0_;                                                 \
        rowacc[1][r_] += e1_;                                                 \
        colsum_ += e0_ + e1_;                                                 \
    }                                                                         \
    colsum_ += __shfl_xor(colsum_, 16);                                       \
    colsum_ += __shfl_xor(colsum_, 32);                                       \
    if (quad == 0) atomicAdd(&colPart[gc_], colsum_); }

    #pragma unroll
    for (int phase = 0; phase < 2; ++phase) {
        const int R  = phase ? (255 - p) : p;   // 32-row tile index 0..255
        const int jj = phase ? (15 - j) : j;    // anti-correlated residue
        const int cb = 2 * R;                   // first 16-col strip with upper cells
        int C = cb + ((jj - cb) & 15);          // first strip ≡ jj (mod 16), >= cb
        if (C >= 512) continue;                 // no strips in this phase

        // A fragments: rows R*32 + rf*16 + m, k = kk*32 + quad*8 (+0..7)
        bf16x8_t afrag[2][8];
        #pragma unroll
        for (int rf = 0; rf < 2; ++rf) {
            const unsigned short* ap =
                zn + (size_t)((R << 5) + rf * 16 + m) * DDIM + quad * 8;
            #pragma unroll
            for (int kk = 0; kk < 8; ++kk)
                afrag[rf][kk] = *reinterpret_cast<const bf16x8_t*>(ap + kk * 32);
        }
        // make A values opaque: compiler cannot rematerialize them from memory
        // (v4's VGPR=88 disaster), must keep all 64 VGPRs live
        #pragma unroll
        for (int rf = 0; rf < 2; ++rf)
            #pragma unroll
            for (int kk = 0; kk < 8; ++kk) {
                int4 t_ = __builtin_bit_cast(int4, afrag[rf][kk]);
                asm volatile("" : "+v"(t_.x), "+v"(t_.y), "+v"(t_.z), "+v"(t_.w));
                afrag[rf][kk] = __builtin_bit_cast(bf16x8_t, t_);
            }

        float rowacc[2][4] = {{0.f,0.f,0.f,0.f},{0.f,0.f,0.f,0.f}};

        // static 2-buffer rotation: issue strip i+1's loads, compute strip i
        bf16x8_t b0[8], b1[8];
        LOADB(b0, C);
        int Cn = C + 16;
        for (;;) {
            if (Cn < 512) LOADB(b1, Cn);
            COMPUTE(b0, C);
            C = Cn; Cn += 16;
            if (C >= 512) break;
            if (Cn < 512) LOADB(b0, Cn);
            COMPUTE(b1, C);
            C = Cn; Cn += 16;
            if (C >= 512) break;
        }

        // row totals: reduce over 16 m-lanes, one atomic per row per phase
        #pragma unroll
        for (int rf = 0; rf < 2; ++rf)
            #pragma unroll
            for (int r = 0; r < 4; ++r) {
                float v = rowacc[rf][r];
                v += __shfl_xor(v, 1);
                v += __shfl_xor(v, 2);
                v += __shfl_xor(v, 4);
                v += __shfl_xor(v, 8);
                if (m == 0)
                    atomicAdd(&rowPart[(R << 5) + rf*16 + quad*4 + r], v);
            }
    }
#undef LOADB
#undef COMPUTE
}

// ---- kernel 3: loss_k = log(sum_p s_part[p][k]) - posdot[k%B]; masked mean ----
__global__ void finalize_kernel(const float* __restrict__ s_part,
                                const float* __restrict__ posdot,
                                const unsigned char* __restrict__ mask,
                                float* __restrict__ out) {
    int tid = threadIdx.x, lane = tid & 63, wv = tid >> 6;
    float tot = 0.f, cnt = 0.f;
    #pragma unroll
    for (int si = 0; si < NTOT / 1024; ++si) {
        int k = si * 1024 + tid;
        int kb = k & (BHALF - 1);
        if (mask[kb] != 0) {
            float sk = s_part[k] + s_part[NTOT + k]
                     + s_part[2*NTOT + k] + s_part[3*NTOT + k];
            tot += __logf(sk) - posdot[kb];
            cnt += 1.f;
        }
    }
    #pragma unroll
    for (int off = 32; off >= 1; off >>= 1) {
        tot += __shfl_xor(tot, off);
        cnt += __shfl_xor(cnt, off);
    }
    __shared__ float st[16], sc[16];
    if (lane == 0) { st[wv] = tot; sc[wv] = cnt; }
    __syncthreads();
    if (tid == 0) {
        float T = 0.f, C = 0.f;
        #pragma unroll
        for (int i = 0; i < 16; ++i) { T += st[i]; C += sc[i]; }
        out[0] = (C > 0.f) ? (T / fmaxf(C, 1.f)) : 0.f;
    }
}

extern "C" void kernel_launch(void* const* d_in, const int* in_sizes, int n_in,
                              void* d_out, int out_size, void* d_ws, size_t ws_size,
                              hipStream_t stream) {
    const float* zi = (const float*)d_in[0];
    const float* zj = (const float*)d_in[1];
    const unsigned char* mask = (const unsigned char*)d_in[2];
    float* out = (float*)d_out;

    // ws: [0,4MB) zn bf16; s_part[NPART][8192] f32; posdot[4096] f32
    unsigned short* zn = (unsigned short*)d_ws;
    float* s_part = (float*)((char*)d_ws + (size_t)NTOT * DDIM * 2);
    float* posdot = s_part + NPART * NTOT;

    norm_pair_kernel<<<dim3(1024), dim3(256), 0, stream>>>(zi, zj, zn, posdot, s_part);
    gemm_sym_kernel<<<dim3(512), dim3(256), 0, stream>>>(zn, s_part);
    finalize_kernel<<<dim3(1), dim3(1024), 0, stream>>>(s_part, posdot, mask, out);
}

// Round 5
// 106.675 us; speedup vs baseline: 1.3593x; 1.3048x over previous
//
#include <hip/hip_runtime.h>
#include <hip/hip_bf16.h>

#define NTOT   8192
#define BHALF  4096
#define DDIM   256
#define SMOD   16     // column-strip stride; grid (32, SMOD)
#define NPART  4      // partial copies of s_arr to spread atomic contention
#define MAXSLOT 9     // max strips per block (pairing bound: f(b)+f(63-b) <= 9)
#define EXPSCALE 14.4269504088896341f   // 10 / ln(2): exp(10x) = exp2(EXPSCALE*x)

typedef __attribute__((ext_vector_type(8))) short bf16x8_t;  // 8 bf16 = 4 VGPRs
typedef __attribute__((ext_vector_type(4))) float f32x4_t;   // MFMA C/D

__device__ inline unsigned short f2bf(float x) {
    __hip_bfloat16 h = __float2bfloat16(x);
    return __builtin_bit_cast(unsigned short, h);
}

// ---- kernel 1: normalize pair k (rows k, k+B) -> bf16 zn; posdot; zero s_part ----
__global__ void norm_pair_kernel(const float* __restrict__ zi,
                                 const float* __restrict__ zj,
                                 unsigned short* __restrict__ zn,
                                 float* __restrict__ posdot,
                                 float* __restrict__ s_part) {
    int gtid = blockIdx.x * 256 + threadIdx.x;
    if (gtid < NTOT * NPART) s_part[gtid] = 0.0f;   // done before gemm (stream order)
    int k    = gtid >> 6;
    int lane = gtid & 63;
    float4 vi = reinterpret_cast<const float4*>(zi + (size_t)k * DDIM)[lane];
    float4 vj = reinterpret_cast<const float4*>(zj + (size_t)k * DDIM)[lane];
    float ssi = vi.x*vi.x + vi.y*vi.y + vi.z*vi.z + vi.w*vi.w;
    float ssj = vj.x*vj.x + vj.y*vj.y + vj.z*vj.z + vj.w*vj.w;
    float dot = vi.x*vj.x + vi.y*vj.y + vi.z*vj.z + vi.w*vj.w;
    #pragma unroll
    for (int off = 32; off >= 1; off >>= 1) {
        ssi += __shfl_xor(ssi, off);
        ssj += __shfl_xor(ssj, off);
        dot += __shfl_xor(dot, off);
    }
    float ri = 1.0f / fmaxf(sqrtf(ssi), 1e-8f);
    float rj = 1.0f / fmaxf(sqrtf(ssj), 1e-8f);
    ushort4 oi, oj;
    oi.x = f2bf(vi.x * ri); oi.y = f2bf(vi.y * ri);
    oi.z = f2bf(vi.z * ri); oi.w = f2bf(vi.w * ri);
    oj.x = f2bf(vj.x * rj); oj.y = f2bf(vj.y * rj);
    oj.z = f2bf(vj.z * rj); oj.w = f2bf(vj.w * rj);
    reinterpret_cast<ushort4*>(zn + (size_t)k * DDIM)[lane] = oi;
    reinterpret_cast<ushort4*>(zn + (size_t)(k + BHALF) * DDIM)[lane] = oj;
    if (lane == 0) posdot[k] = dot * ri * rj * 10.0f;
}

// ---- kernel 2: symmetric fused GEMM + exp-sum, v6: v2 + T3/T4/T5 phase split ----
// v2 (45.6us): strip body = [all ds_reads] -> [all MFMA] -> [all exp2] executed
// as a convoy; every pipe <35% busy. v4/v5 (reg-stream, 74-80us): per-strip
// atomics act as vmcnt fences (in-order retirement) -- abandoned. v6 keeps v2's
// block/strip geometry + LDS dbuf + gl_lds staging + buffered colsums, and
// splits each strip into 4 phases (one per cf, 16 MFMA each, m201 template):
//   {8 ds_read_b128; issue 2 gl_lds of next strip; barrier;
//    setprio(1); 16 MFMA; setprio(0); fused exp2 epilogue; barrier}
// Per-phase barriers pace waves so one wave's ds_reads co-schedule with
// another's MFMAs (T3); vmcnt(0) once per strip, pre-satisfied (loads issued
// 4 phases earlier = T4 counted-vmcnt effect); setprio arbitrates (T5, only
// pays on phase-split schedules per m218b). All barrier paths block-uniform.
__global__ void __launch_bounds__(256, 2)
gemm_sym_kernel(const unsigned short* __restrict__ zn,
                float* __restrict__ s_part) {
    __shared__ unsigned short ldsB[2][64 * 256];   // 2 x 32 KB double buffer
    __shared__ float colLDS[MAXSLOT][4][64];       // 9 KB

    const int tid  = threadIdx.x;
    const int lane = tid & 63;
    const int wv   = tid >> 6;        // 0..3 -> 32-row slice of the 128-row block
    const int m    = lane & 15;
    const int quad = lane >> 4;
    const int biA  = blockIdx.x;      // 0..31
    const int s    = blockIdx.y;      // 0..15

    float* rowPart = s_part + (size_t)(s   & (NPART - 1)) * NTOT;
    float* colPart = s_part + (size_t)(biA & (NPART - 1)) * NTOT;

// issue gl_lds for staging chunks t0..t0+1 of strip C1 into dst (linear LDS
// dest; xor-swizzle on the GLOBAL source chunk index -- both-sides rule)
#define STAGE2(dst, C1, t0) {                                                 \
    _Pragma("unroll")                                                         \
    for (int t_ = (t0); t_ < (t0) + 2; ++t_) {                                \
        int ci_ = t_ * 256 + tid;                                             \
        int r_ = ci_ >> 5, c_ = ci_ & 31;                                     \
        const unsigned short* g_ =                                            \
            zn + (size_t)((C1) + r_) * DDIM + ((c_ ^ (r_ & 7)) << 3);         \
        __builtin_amdgcn_global_load_lds(                                     \
            (const __attribute__((address_space(1))) unsigned int*)g_,        \
            (__attribute__((address_space(3))) unsigned int*)                 \
                ((dst) + (size_t)ci_ * 8),                                    \
            16, 0, 0);                                                        \
    } }

    int slot = 0;
    #pragma unroll
    for (int p = 0; p < 2; ++p) {
        const int bi = p ? (63 - biA) : biA;
        const int R0 = bi << 7;
        const int cs0 = 2 * bi + ((s - 2 * bi) & (SMOD - 1));
        if (cs0 >= 128) continue;     // block-uniform: no divergence hazard

        // A fragments: rows R0 + wv*32 + rf*16 + m, k = kk*32 + quad*8 (+j)
        bf16x8_t afrag[2][8];
        #pragma unroll
        for (int rf = 0; rf < 2; ++rf) {
            const unsigned short* arow = zn + (size_t)(R0 + wv*32 + rf*16 + m) * DDIM;
            #pragma unroll
            for (int kk = 0; kk < 8; ++kk)
                afrag[rf][kk] = *reinterpret_cast<const bf16x8_t*>(arow + kk*32 + quad*8);
        }

        float rowacc[2][4] = {{0.f,0.f,0.f,0.f},{0.f,0.f,0.f,0.f}};

        // prologue: stage first strip of this phase into buffer 0
        STAGE2(ldsB[0], cs0 << 6, 0);
        STAGE2(ldsB[0], cs0 << 6, 2);
        STAGE2(ldsB[0], cs0 << 6, 4);
        STAGE2(ldsB[0], cs0 << 6, 6);

        int cur = 0;
        for (int cs = cs0; cs < 128; cs += SMOD) {
            const int C0 = cs << 6;
            const bool isDiag  = ((cs >> 1) == bi);
            const bool haveNxt = (cs + SMOD < 128);
            const int  C1      = (cs + SMOD) << 6;
            unsigned short* nxt = ldsB[cur ^ 1];
            const unsigned short* Bt = ldsB[cur];

            // buf[cur] staged (my 8 gl_lds; all issued >=1 strip ago); barrier
            // makes everyone's portion visible + certifies buf[cur^1] reads done
            asm volatile("s_waitcnt vmcnt(0)" ::: "memory");
            __builtin_amdgcn_s_barrier();
            __builtin_amdgcn_sched_barrier(0);

            #pragma unroll
            for (int cf = 0; cf < 4; ++cf) {
                // phase: ds-read this cf's B-frags
                bf16x8_t bfr[8];
                #pragma unroll
                for (int kk = 0; kk < 8; ++kk)
                    bfr[kk] = *reinterpret_cast<const bf16x8_t*>(
                        Bt + (cf*16 + m) * 256 + (((kk*4 + quad) ^ (m & 7)) << 3));
                // issue 2 of next strip's 8 staging chunks
                if (haveNxt) STAGE2(nxt, C1, cf * 2);
                __builtin_amdgcn_sched_barrier(0);
                __builtin_amdgcn_s_barrier();
                __builtin_amdgcn_sched_barrier(0);

                __builtin_amdgcn_s_setprio(1);
                f32x4_t c0 = (f32x4_t){0.f,0.f,0.f,0.f};
                f32x4_t c1 = (f32x4_t){0.f,0.f,0.f,0.f};
                #pragma unroll
                for (int kk = 0; kk < 8; ++kk) {
                    c0 = __builtin_amdgcn_mfma_f32_16x16x32_bf16(afrag[0][kk], bfr[kk], c0, 0, 0, 0);
                    c1 = __builtin_amdgcn_mfma_f32_16x16x32_bf16(afrag[1][kk], bfr[kk], c1, 0, 0, 0);
                }
                __builtin_amdgcn_s_setprio(0);

                // fused epilogue for this cf
                const int gc = C0 + cf*16 + m;
                float colsum = 0.f;
                #pragma unroll
                for (int r = 0; r < 4; ++r) {
                    int gr0 = R0 + wv*32 + quad*4 + r;
                    float e0 = exp2f(c0[r] * EXPSCALE);
                    float e1 = exp2f(c1[r] * EXPSCALE);
                    if (isDiag && gr0 == gc)        e0 = 0.f;
                    if (isDiag && (gr0 + 16) == gc) e1 = 0.f;
                    rowacc[0][r] += e0;
                    rowacc[1][r] += e1;
                    colsum += e0 + e1;
                }
                if (!isDiag) {
                    colsum += __shfl_xor(colsum, 16);
                    colsum += __shfl_xor(colsum, 32);
                    if (quad == 0) colLDS[slot][wv][cf*16 + m] = colsum;
                }
                __builtin_amdgcn_sched_barrier(0);
                __builtin_amdgcn_s_barrier();
            }
            cur ^= 1;
            ++slot;
        }

        // row totals for this phase: reduce over 16 m-lanes, one atomic per row
        #pragma unroll
        for (int rf = 0; rf < 2; ++rf)
            #pragma unroll
            for (int r = 0; r < 4; ++r) {
                float v = rowacc[rf][r];
                v += __shfl_xor(v, 1);
                v += __shfl_xor(v, 2);
                v += __shfl_xor(v, 4);
                v += __shfl_xor(v, 8);
                if (m == 0)
                    atomicAdd(&rowPart[R0 + wv*32 + rf*16 + quad*4 + r], v);
            }

        // all reads of ldsB done before next phase's prologue overwrites buf 0
        __builtin_amdgcn_s_barrier();
        __builtin_amdgcn_sched_barrier(0);
    }
#undef STAGE2

    // drain this wave's colLDS ds_writes, then make them visible to the flush
    asm volatile("s_waitcnt lgkmcnt(0)" ::: "memory");
    __builtin_amdgcn_s_barrier();
    __builtin_amdgcn_sched_barrier(0);

    // flush column sums: re-enumerate strips in the same order
    if (tid < 64) {
        int slot2 = 0;
        #pragma unroll
        for (int p = 0; p < 2; ++p) {
            const int bi = p ? (63 - biA) : biA;
            const int cs0 = 2 * bi + ((s - 2 * bi) & (SMOD - 1));
            if (cs0 >= 128) continue;
            for (int cs = cs0; cs < 128; cs += SMOD) {
                if ((cs >> 1) != bi) {
                    float v = colLDS[slot2][0][tid] + colLDS[slot2][1][tid]
                            + colLDS[slot2][2][tid] + colLDS[slot2][3][tid];
                    atomicAdd(&colPart[(cs << 6) + tid], v);
                }
                ++slot2;
            }
        }
    }
}

// ---- kernel 3: loss_k = log(sum_p s_part[p][k]) - posdot[k%B]; masked mean ----
__global__ void finalize_kernel(const float* __restrict__ s_part,
                                const float* __restrict__ posdot,
                                const unsigned char* __restrict__ mask,
                                float* __restrict__ out) {
    int tid = threadIdx.x, lane = tid & 63, wv = tid >> 6;
    float tot = 0.f, cnt = 0.f;
    #pragma unroll
    for (int si = 0; si < NTOT / 1024; ++si) {
        int k = si * 1024 + tid;
        int kb = k & (BHALF - 1);
        if (mask[kb] != 0) {
            float sk = s_part[k] + s_part[NTOT + k]
                     + s_part[2*NTOT + k] + s_part[3*NTOT + k];
            tot += __logf(sk) - posdot[kb];
            cnt += 1.f;
        }
    }
    #pragma unroll
    for (int off = 32; off >= 1; off >>= 1) {
        tot += __shfl_xor(tot, off);
        cnt += __shfl_xor(cnt, off);
    }
    __shared__ float st[16], sc[16];
    if (lane == 0) { st[wv] = tot; sc[wv] = cnt; }
    __syncthreads();
    if (tid == 0) {
        float T = 0.f, C = 0.f;
        #pragma unroll
        for (int i = 0; i < 16; ++i) { T += st[i]; C += sc[i]; }
        out[0] = (C > 0.f) ? (T / fmaxf(C, 1.f)) : 0.f;
    }
}

extern "C" void kernel_launch(void* const* d_in, const int* in_sizes, int n_in,
                              void* d_out, int out_size, void* d_ws, size_t ws_size,
                              hipStream_t stream) {
    const float* zi = (const float*)d_in[0];
    const float* zj = (const float*)d_in[1];
    const unsigned char* mask = (const unsigned char*)d_in[2];
    float* out = (float*)d_out;

    // ws: [0,4MB) zn bf16; s_part[NPART][8192] f32; posdot[4096] f32
    unsigned short* zn = (unsigned short*)d_ws;
    float* s_part = (float*)((char*)d_ws + (size_t)NTOT * DDIM * 2);
    float* posdot = s_part + NPART * NTOT;

    norm_pair_kernel<<<dim3(1024), dim3(256), 0, stream>>>(zi, zj, zn, posdot, s_part);
    gemm_sym_kernel<<<dim3(32, SMOD), dim3(256), 0, stream>>>(zn, s_part);
    finalize_kernel<<<dim3(1), dim3(1024), 0, stream>>>(s_part, posdot, mask, out);
}